// Round 1
// baseline (365.622 us; speedup 1.0000x reference)
//
#include <hip/hip_runtime.h>
#include <math.h>

#define NFEAT 32
#define EMB   30
#define ATT   10
#define NPAIR 496   // 32*31/2
#define BLK   256
#define WPB   4     // waves per block = batch elements per block
#define ROWSTR 36   // padded x-row stride in floats (144B, 16B-aligned)
#define WROW  12    // padded W row: [0..9]=W, [10]=pvec, [11]=0

// __launch_bounds__(256,4): 4 waves/EU -> 4 blocks/CU, caps VGPR at 128
// (was 204 -> only 2 waves/SIMD -> latency-bound, VALUBusy 47%).
__global__ __launch_bounds__(BLK, 4)
void attn_net_kernel(const float* __restrict__ x,
                     const float* __restrict__ W,
                     const float* __restrict__ bias,
                     const float* __restrict__ h,
                     const float* __restrict__ pvec,
                     float* __restrict__ out)
{
    __shared__ __align__(16) float sx[WPB * NFEAT * ROWSTR];  // 4*1152 floats
    __shared__ __align__(16) float sWp[32 * WROW];            // rows 30,31 zero
    __shared__ __align__(16) float sb2[12];                   // [10..11]=0 (c-accumulator bias)
    __shared__ __align__(16) float sh2[12];
    __shared__ unsigned int lut[NPAIR];                       // (36*i) | (36*j)<<16 dword offsets

    const int t    = threadIdx.x;
    const int wid  = t >> 6;
    const int lane = t & 63;
    const int b    = blockIdx.x * WPB + wid;

    // ---- stage constants (block-wide, padded with zeros) ----
    for (int q = t; q < 32 * WROW; q += BLK) {
        const int e = q / WROW, a = q - e * WROW;
        float v = 0.f;
        if (e < EMB) {
            if (a < ATT)       v = W[e * ATT + a];
            else if (a == ATT) v = pvec[e];
        }
        sWp[q] = v;
    }
    if (t < 12) {
        sb2[t] = (t < ATT) ? bias[t] : 0.f;
        sh2[t] = (t < ATT) ? h[t]    : 0.f;
    }
    // ---- pair LUT (row-major triu k=1 order) ----
    for (int p = t; p < NPAIR; p += BLK) {
        int i = 0, rem = p;
        while (rem >= NFEAT - 1 - i) { rem -= NFEAT - 1 - i; ++i; }
        const int j = i + 1 + rem;
        lut[p] = (unsigned)(i * ROWSTR) | ((unsigned)(j * ROWSTR) << 16);
    }

    // ---- stage x[b] into this wave's padded LDS rows ----
    float* swx = sx + wid * (NFEAT * ROWSTR);
    {
        // zero pad cols 30..35 (each lane zeroes 3)
        const int zr = lane >> 1, zc = 30 + (lane & 1) * 3;
        swx[zr * ROWSTR + zc + 0] = 0.f;
        swx[zr * ROWSTR + zc + 1] = 0.f;
        swx[zr * ROWSTR + zc + 2] = 0.f;
        const float4* xin = reinterpret_cast<const float4*>(x + (size_t)b * (NFEAT * EMB));
        for (int v = lane; v < 240; v += 64) {
            const float4 d = xin[v];
            const int ef = 4 * v;
            #pragma unroll
            for (int u = 0; u < 4; ++u) {
                const int e = ef + u;
                const int r = e / EMB;
                const int c = e - r * EMB;
                swx[r * ROWSTR + c] = ((const float*)&d)[u];
            }
        }
    }
    __syncthreads();

    // ---- per-lane: up to 8 pairs, 2 chunks of 4; softmax carried ONLINE in
    //      (m, se, sec) so no score[8]/cval[8] arrays stay live (reg pressure) ----
    float m = -INFINITY, se = 0.f, sec = 0.f;

    #pragma unroll
    for (int ch = 0; ch < 2; ++ch) {
        const int kb = ch * 4;
        int oi[4], oj[4];
        #pragma unroll
        for (int k = 0; k < 4; ++k) {
            int p = lane + 64 * (kb + k);
            if (p > NPAIR - 1) p = NPAIR - 1;           // tail lanes: masked to -inf later
            const unsigned L = lut[p];
            oi[k] = (int)(L & 0xffffu);
            oj[k] = (int)(L >> 16);
        }

        float acc[4][11];
        #pragma unroll
        for (int a = 0; a < 11; ++a) {
            const float bv = sb2[a];                    // broadcast; sb2[10]=0 -> c accumulator
            #pragma unroll
            for (int k = 0; k < 4; ++k) acc[k][a] = bv;
        }

        #pragma unroll
        for (int eg = 0; eg < 8; ++eg) {                // e in groups of 4, padded to 32
            float4 xi4[4], xj4[4];
            #pragma unroll
            for (int k = 0; k < 4; ++k) {
                xi4[k] = *reinterpret_cast<const float4*>(&swx[oi[k] + eg * 4]);
                xj4[k] = *reinterpret_cast<const float4*>(&swx[oj[k] + eg * 4]);
            }
            #pragma unroll
            for (int t4 = 0; t4 < 4; ++t4) {
                const int e = eg * 4 + t4;
                const float4 wA = *reinterpret_cast<const float4*>(&sWp[e * WROW + 0]);
                const float4 wB = *reinterpret_cast<const float4*>(&sWp[e * WROW + 4]);
                const float4 wC = *reinterpret_cast<const float4*>(&sWp[e * WROW + 8]);
                #pragma unroll
                for (int k = 0; k < 4; ++k) {
                    const float pe = ((const float*)&xi4[k])[t4] * ((const float*)&xj4[k])[t4];
                    acc[k][0]  = fmaf(pe, wA.x, acc[k][0]);
                    acc[k][1]  = fmaf(pe, wA.y, acc[k][1]);
                    acc[k][2]  = fmaf(pe, wA.z, acc[k][2]);
                    acc[k][3]  = fmaf(pe, wA.w, acc[k][3]);
                    acc[k][4]  = fmaf(pe, wB.x, acc[k][4]);
                    acc[k][5]  = fmaf(pe, wB.y, acc[k][5]);
                    acc[k][6]  = fmaf(pe, wB.z, acc[k][6]);
                    acc[k][7]  = fmaf(pe, wB.w, acc[k][7]);
                    acc[k][8]  = fmaf(pe, wC.x, acc[k][8]);
                    acc[k][9]  = fmaf(pe, wC.y, acc[k][9]);
                    acc[k][10] = fmaf(pe, wC.z, acc[k][10]);   // wC.z = pvec[e]
                }
            }
        }

        float hreg[10];
        #pragma unroll
        for (int a = 0; a < ATT; ++a) hreg[a] = sh2[a]; // broadcast, transient
        float s[4], cv[4];
        #pragma unroll
        for (int k = 0; k < 4; ++k) {
            float sc = 0.f;
            #pragma unroll
            for (int a = 0; a < ATT; ++a)
                sc = fmaf(fmaxf(acc[k][a], 0.f), hreg[a], sc);
            s[k]  = sc;
            cv[k] = acc[k][10];
        }
        // mask tail pairs (only ch==1, k==3 on lanes >= 48)
        #pragma unroll
        for (int k = 0; k < 4; ++k)
            if (lane + 64 * (kb + k) >= NPAIR) s[k] = -INFINITY;

        // online merge into (m, se, sec); chunk 0: m=-inf -> scale=0, se/sec start clean
        const float cm = fmaxf(fmaxf(s[0], s[1]), fmaxf(s[2], s[3]));
        const float nm = fmaxf(m, cm);
        const float scale = __expf(m - nm);
        se  *= scale;
        sec *= scale;
        #pragma unroll
        for (int k = 0; k < 4; ++k) {
            const float E = __expf(s[k] - nm);          // exp(-inf)=0 for masked
            se += E;
            sec = fmaf(E, cv[k], sec);
        }
        m = nm;
    }

    // ---- cross-lane merge of (m, se, sec): 6-stage butterfly, no barriers ----
    #pragma unroll
    for (int o = 1; o < 64; o <<= 1) {
        const float om  = __shfl_xor(m,   o, 64);
        const float ose = __shfl_xor(se,  o, 64);
        const float osc = __shfl_xor(sec, o, 64);
        const float nm  = fmaxf(m, om);
        const float ea  = __expf(m  - nm);
        const float eb  = __expf(om - nm);
        se  = fmaf(se,  ea, ose * eb);
        sec = fmaf(sec, ea, osc * eb);
        m = nm;
    }
    if (lane == 0) out[b] = sec / se;
}

extern "C" void kernel_launch(void* const* d_in, const int* in_sizes, int n_in,
                              void* d_out, int out_size, void* d_ws, size_t ws_size,
                              hipStream_t stream) {
    const float* x    = (const float*)d_in[0];
    const float* W    = (const float*)d_in[1];
    const float* bias = (const float*)d_in[2];
    const float* h    = (const float*)d_in[3];
    const float* pvec = (const float*)d_in[4];
    float* out = (float*)d_out;

    const int B = in_sizes[0] / (NFEAT * EMB);   // 8192
    attn_net_kernel<<<B / WPB, BLK, 0, stream>>>(x, W, bias, h, pvec, out);
}

// Round 2
// 61.512 us; speedup vs baseline: 5.9439x; 5.9439x over previous
//
#include <hip/hip_runtime.h>
#include <math.h>

#define NFEAT 32
#define EMB   30
#define ATT   10
#define NPAIR 496   // 32*31/2
#define BLK   256
#define WPB   4     // waves per block = batch elements per block
#define ROWSTR 36   // padded x-row stride in floats (144B; 4-bank shift per row)

typedef float v2f __attribute__((ext_vector_type(2)));

// Slim body (~105 est. live VGPRs) + native waves_per_eu(4) => cap 128.
// Round-1 lesson: __launch_bounds__(256,4) mapped to a 64-VGPR cap and the
// 204-reg body spilled catastrophically (WRITE_SIZE 64KB->651MB).
__global__ __launch_bounds__(BLK) __attribute__((amdgpu_waves_per_eu(4)))
void attn_net_kernel(const float* __restrict__ x,
                     const float* __restrict__ W,
                     const float* __restrict__ bias,
                     const float* __restrict__ h,
                     const float* __restrict__ pvec,
                     float* __restrict__ out)
{
    __shared__ __align__(16) float sx[WPB * NFEAT * ROWSTR];  // 18 KiB, wave-private slices

    const int t    = threadIdx.x;
    const int wid  = t >> 6;
    const int lane = t & 63;
    const int b    = blockIdx.x * WPB + wid;

    // ---- stage x[b] into this wave's padded LDS rows (wave-private: NO barrier) ----
    float* swx = sx + wid * (NFEAT * ROWSTR);
    {
        // zero pad cols 30..35 (each lane zeroes 3)
        const int zr = lane >> 1, zc = 30 + (lane & 1) * 3;
        swx[zr * ROWSTR + zc + 0] = 0.f;
        swx[zr * ROWSTR + zc + 1] = 0.f;
        swx[zr * ROWSTR + zc + 2] = 0.f;
        const float4* xin = reinterpret_cast<const float4*>(x + (size_t)b * (NFEAT * EMB));
        for (int v = lane; v < 240; v += 64) {
            const float4 d = xin[v];
            const int ef = 4 * v;
            #pragma unroll
            for (int u = 0; u < 4; ++u) {
                const int e = ef + u;
                const int r = e / EMB;
                const int c = e - r * EMB;
                swx[r * ROWSTR + c] = ((const float*)&d)[u];
            }
        }
    }

    // ---- uniform params -> SGPRs (scalar loads; no LDS, no VGPR cost) ----
    v2f b2[5], h2[5];
    #pragma unroll
    for (int a2 = 0; a2 < 5; ++a2) {
        b2[a2].x = bias[2 * a2]; b2[a2].y = bias[2 * a2 + 1];
        h2[a2].x = h[2 * a2];    h2[a2].y = h[2 * a2 + 1];
    }

    // ---- per-lane: 8 pairs in 2 chunks of 4; online softmax in (m,se,sec) ----
    float m = -INFINITY, se = 0.f, sec = 0.f;

    #pragma unroll
    for (int ch = 0; ch < 2; ++ch) {
        // closed-form triu index: p -> (i,j).  At row starts 3969-8p=(63-2i)^2
        // (perfect square), so sqrt is exact; fixups guard rounding anyway.
        int oi[4], oj[4];
        #pragma unroll
        for (int k = 0; k < 4; ++k) {
            int p = lane + 64 * (ch * 4 + k);
            if (p > NPAIR - 1) p = NPAIR - 1;          // tail lanes masked below
            int i = (int)((63.0f - sqrtf((float)(3969 - 8 * p))) * 0.5f);
            if (i * (63 - i) / 2 > p) --i;
            if ((i + 1) * (62 - i) / 2 <= p) ++i;
            const int j = i + 1 + (p - i * (63 - i) / 2);
            oi[k] = i * ROWSTR;
            oj[k] = j * ROWSTR;
        }

        v2f   acc2[4][5];                               // packed f32 accumulators
        float accC[4];                                  // pvec-weighted c
        #pragma unroll
        for (int k = 0; k < 4; ++k) {
            #pragma unroll
            for (int a2 = 0; a2 < 5; ++a2) acc2[k][a2] = b2[a2];
            accC[k] = 0.f;
        }

        #pragma unroll
        for (int eg = 0; eg < 8; ++eg) {                // e-groups of 4; eg=7 -> e=28,29 only
            float4 pr[4];
            #pragma unroll
            for (int k = 0; k < 4; ++k) {
                const float4 xi = *reinterpret_cast<const float4*>(&swx[oi[k] + eg * 4]);
                const float4 xj = *reinterpret_cast<const float4*>(&swx[oj[k] + eg * 4]);
                pr[k].x = xi.x * xj.x; pr[k].y = xi.y * xj.y;
                pr[k].z = xi.z * xj.z; pr[k].w = xi.w * xj.w;
            }
            const int TMAX = (eg == 7) ? 2 : 4;         // no W rows >= 30 (avoid OOB s_load)
            #pragma unroll
            for (int t4 = 0; t4 < TMAX; ++t4) {
                const int e = eg * 4 + t4;
                v2f w01, w23, w45, w67, w89;            // uniform -> SGPR pairs
                w01.x = W[e * ATT + 0]; w01.y = W[e * ATT + 1];
                w23.x = W[e * ATT + 2]; w23.y = W[e * ATT + 3];
                w45.x = W[e * ATT + 4]; w45.y = W[e * ATT + 5];
                w67.x = W[e * ATT + 6]; w67.y = W[e * ATT + 7];
                w89.x = W[e * ATT + 8]; w89.y = W[e * ATT + 9];
                const float pv = pvec[e];
                #pragma unroll
                for (int k = 0; k < 4; ++k) {
                    const float pe = (t4 == 0) ? pr[k].x : (t4 == 1) ? pr[k].y
                                   : (t4 == 2) ? pr[k].z : pr[k].w;
                    v2f pe2; pe2.x = pe; pe2.y = pe;
                    acc2[k][0] = __builtin_elementwise_fma(pe2, w01, acc2[k][0]);
                    acc2[k][1] = __builtin_elementwise_fma(pe2, w23, acc2[k][1]);
                    acc2[k][2] = __builtin_elementwise_fma(pe2, w45, acc2[k][2]);
                    acc2[k][3] = __builtin_elementwise_fma(pe2, w67, acc2[k][3]);
                    acc2[k][4] = __builtin_elementwise_fma(pe2, w89, acc2[k][4]);
                    accC[k]    = fmaf(pe, pv, accC[k]);
                }
            }
        }

        float s4[4], cv4[4];
        #pragma unroll
        for (int k = 0; k < 4; ++k) {
            v2f z;  z.x = 0.f; z.y = 0.f;
            v2f sv; sv.x = 0.f; sv.y = 0.f;
            #pragma unroll
            for (int a2 = 0; a2 < 5; ++a2) {
                const v2f r = __builtin_elementwise_max(acc2[k][a2], z);
                sv = __builtin_elementwise_fma(r, h2[a2], sv);
            }
            s4[k]  = sv.x + sv.y;
            cv4[k] = accC[k];
            if (lane + 64 * (ch * 4 + k) >= NPAIR) s4[k] = -INFINITY;
        }

        // online merge (ch=0: m=-inf -> scale=0, clean start)
        const float cm = fmaxf(fmaxf(s4[0], s4[1]), fmaxf(s4[2], s4[3]));
        const float nm = fmaxf(m, cm);
        const float scale = __expf(m - nm);
        se  *= scale;
        sec *= scale;
        #pragma unroll
        for (int k = 0; k < 4; ++k) {
            const float E = __expf(s4[k] - nm);         // exp(-inf)=0 for masked
            se += E;
            sec = fmaf(E, cv4[k], sec);
        }
        m = nm;
    }

    // ---- cross-lane merge of (m,se,sec): 6-stage butterfly, no barriers ----
    #pragma unroll
    for (int o = 1; o < 64; o <<= 1) {
        const float om  = __shfl_xor(m,   o, 64);
        const float ose = __shfl_xor(se,  o, 64);
        const float osc = __shfl_xor(sec, o, 64);
        const float nm  = fmaxf(m, om);
        const float ea  = __expf(m  - nm);
        const float eb  = __expf(om - nm);
        se  = fmaf(se,  ea, ose * eb);
        sec = fmaf(sec, ea, osc * eb);
        m = nm;
    }
    if (lane == 0) out[b] = sec / se;
}

extern "C" void kernel_launch(void* const* d_in, const int* in_sizes, int n_in,
                              void* d_out, int out_size, void* d_ws, size_t ws_size,
                              hipStream_t stream) {
    const float* x    = (const float*)d_in[0];
    const float* W    = (const float*)d_in[1];
    const float* bias = (const float*)d_in[2];
    const float* h    = (const float*)d_in[3];
    const float* pvec = (const float*)d_in[4];
    float* out = (float*)d_out;

    const int B = in_sizes[0] / (NFEAT * EMB);   // 8192
    attn_net_kernel<<<B / WPB, BLK, 0, stream>>>(x, W, bias, h, pvec, out);
}

// Round 4
// 56.433 us; speedup vs baseline: 6.4788x; 1.0900x over previous
//
#include <hip/hip_runtime.h>
#include <math.h>

#define NFEAT 32
#define EMB   30
#define ATT   10
#define NPAIR 496   // 32*31/2
#define BLK   256
#define WPB   4     // waves per block = batch elements per block
#define ROWSTR 36   // padded x-row stride in floats (144B; 4-bank shift per row)

typedef float v2f __attribute__((ext_vector_type(2)));

// Round-2 lesson: on this toolchain waves_per_eu(4) == 64-VGPR cap (not 128);
// the k=4 body (~75 live) spilled 118MB to scratch -> traffic-bound.
// Round-3 lesson: staging must iterate exactly 240 float4s (bounded loop);
// the unconditional 4x64 unroll read 256 and wrote LDS rows r>31 -> abort.
// k=2 pairs/chunk x 4 chunks => ~45 live VGPRs, fits 64 cap, no spill,
// 8 waves/SIMD (LDS 18KiB -> 8 blocks/CU).
__global__ __launch_bounds__(BLK) __attribute__((amdgpu_waves_per_eu(4)))
void attn_net_kernel(const float* __restrict__ x,
                     const float* __restrict__ W,
                     const float* __restrict__ bias,
                     const float* __restrict__ h,
                     const float* __restrict__ pvec,
                     float* __restrict__ out)
{
    __shared__ __align__(16) float sx[WPB * NFEAT * ROWSTR];  // 18 KiB, wave-private slices

    const int t    = threadIdx.x;
    const int wid  = t >> 6;
    const int lane = t & 63;
    const int b    = blockIdx.x * WPB + wid;

    // ---- stage x[b] into this wave's padded LDS rows (wave-private: NO barrier).
    //      cols 30..35 uninitialized: eg=7 only consumes t4<2 (e=28,29). ----
    float* swx = sx + wid * (NFEAT * ROWSTR);
    {
        const float4* xin = reinterpret_cast<const float4*>(x + (size_t)b * (NFEAT * EMB));
        for (int v = lane; v < 240; v += 64) {          // exactly 240 float4s = 960 floats
            const float4 d = xin[v];
            const int ef = 4 * v;
            #pragma unroll
            for (int u = 0; u < 4; ++u) {
                const int e = ef + u;
                const int r = e / EMB;
                const int c = e - r * EMB;
                swx[r * ROWSTR + c] = ((const float*)&d)[u];
            }
        }
    }

    // ---- uniform params (scalar loads -> SGPRs) ----
    v2f b2[5], h2[5];
    #pragma unroll
    for (int a2 = 0; a2 < 5; ++a2) {
        b2[a2].x = bias[2 * a2]; b2[a2].y = bias[2 * a2 + 1];
        h2[a2].x = h[2 * a2];    h2[a2].y = h[2 * a2 + 1];
    }

    // ---- per-lane: 8 pairs in 4 chunks of 2; online softmax in (m,se,sec) ----
    float m = -INFINITY, se = 0.f, sec = 0.f;

    #pragma unroll
    for (int ch = 0; ch < 4; ++ch) {
        // closed-form triu index p -> (i,j); 3969-8p=(63-2i)^2 exact at row starts
        int oi[2], oj[2];
        #pragma unroll
        for (int k = 0; k < 2; ++k) {
            int p = lane + 64 * (ch * 2 + k);
            if (p > NPAIR - 1) p = NPAIR - 1;          // tail lanes masked below
            int i = (int)((63.0f - sqrtf((float)(3969 - 8 * p))) * 0.5f);
            if (i * (63 - i) / 2 > p) --i;
            if ((i + 1) * (62 - i) / 2 <= p) ++i;
            const int j = i + 1 + (p - i * (63 - i) / 2);
            oi[k] = i * ROWSTR;
            oj[k] = j * ROWSTR;
        }

        v2f   acc2[2][5];                               // packed f32 accumulators (20 VGPR)
        float accC[2];                                  // pvec-weighted c
        #pragma unroll
        for (int k = 0; k < 2; ++k) {
            #pragma unroll
            for (int a2 = 0; a2 < 5; ++a2) acc2[k][a2] = b2[a2];
            accC[k] = 0.f;
        }

        #pragma unroll
        for (int eg = 0; eg < 8; ++eg) {                // e-groups of 4; eg=7 -> e=28,29 only
            float4 pr[2];
            #pragma unroll
            for (int k = 0; k < 2; ++k) {
                const float4 xi = *reinterpret_cast<const float4*>(&swx[oi[k] + eg * 4]);
                const float4 xj = *reinterpret_cast<const float4*>(&swx[oj[k] + eg * 4]);
                pr[k].x = xi.x * xj.x; pr[k].y = xi.y * xj.y;
                pr[k].z = xi.z * xj.z; pr[k].w = xi.w * xj.w;
            }
            const int TMAX = (eg == 7) ? 2 : 4;         // no W rows >= 30
            #pragma unroll
            for (int t4 = 0; t4 < TMAX; ++t4) {
                const int e = eg * 4 + t4;
                v2f w01, w23, w45, w67, w89;            // uniform -> SGPR pairs
                w01.x = W[e * ATT + 0]; w01.y = W[e * ATT + 1];
                w23.x = W[e * ATT + 2]; w23.y = W[e * ATT + 3];
                w45.x = W[e * ATT + 4]; w45.y = W[e * ATT + 5];
                w67.x = W[e * ATT + 6]; w67.y = W[e * ATT + 7];
                w89.x = W[e * ATT + 8]; w89.y = W[e * ATT + 9];
                const float pv = pvec[e];
                #pragma unroll
                for (int k = 0; k < 2; ++k) {
                    const float pe = (t4 == 0) ? pr[k].x : (t4 == 1) ? pr[k].y
                                   : (t4 == 2) ? pr[k].z : pr[k].w;
                    v2f pe2; pe2.x = pe; pe2.y = pe;
                    acc2[k][0] = __builtin_elementwise_fma(pe2, w01, acc2[k][0]);
                    acc2[k][1] = __builtin_elementwise_fma(pe2, w23, acc2[k][1]);
                    acc2[k][2] = __builtin_elementwise_fma(pe2, w45, acc2[k][2]);
                    acc2[k][3] = __builtin_elementwise_fma(pe2, w67, acc2[k][3]);
                    acc2[k][4] = __builtin_elementwise_fma(pe2, w89, acc2[k][4]);
                    accC[k]    = fmaf(pe, pv, accC[k]);
                }
            }
        }

        float s2[2], cv2[2];
        #pragma unroll
        for (int k = 0; k < 2; ++k) {
            v2f z;  z.x = 0.f; z.y = 0.f;
            v2f sv; sv.x = 0.f; sv.y = 0.f;
            #pragma unroll
            for (int a2 = 0; a2 < 5; ++a2) {
                const v2f r = __builtin_elementwise_max(acc2[k][a2], z);
                sv = __builtin_elementwise_fma(r, h2[a2], sv);
            }
            s2[k]  = sv.x + sv.y;
            cv2[k] = accC[k];
            if (lane + 64 * (ch * 2 + k) >= NPAIR) s2[k] = -INFINITY;
        }

        // online merge (ch=0: m=-inf -> scale=0, clean start)
        const float nm = fmaxf(m, fmaxf(s2[0], s2[1]));
        const float scale = __expf(m - nm);
        se  *= scale;
        sec *= scale;
        #pragma unroll
        for (int k = 0; k < 2; ++k) {
            const float E = __expf(s2[k] - nm);         // exp(-inf)=0 for masked
            se += E;
            sec = fmaf(E, cv2[k], sec);
        }
        m = nm;
    }

    // ---- cross-lane merge of (m,se,sec): 6-stage butterfly, no barriers ----
    #pragma unroll
    for (int o = 1; o < 64; o <<= 1) {
        const float om  = __shfl_xor(m,   o, 64);
        const float ose = __shfl_xor(se,  o, 64);
        const float osc = __shfl_xor(sec, o, 64);
        const float nm  = fmaxf(m, om);
        const float ea  = __expf(m  - nm);
        const float eb  = __expf(om - nm);
        se  = fmaf(se,  ea, ose * eb);
        sec = fmaf(sec, ea, osc * eb);
        m = nm;
    }
    if (lane == 0) out[b] = sec / se;
}

extern "C" void kernel_launch(void* const* d_in, const int* in_sizes, int n_in,
                              void* d_out, int out_size, void* d_ws, size_t ws_size,
                              hipStream_t stream) {
    const float* x    = (const float*)d_in[0];
    const float* W    = (const float*)d_in[1];
    const float* bias = (const float*)d_in[2];
    const float* h    = (const float*)d_in[3];
    const float* pvec = (const float*)d_in[4];
    float* out = (float*)d_out;

    const int B = in_sizes[0] / (NFEAT * EMB);   // 8192
    attn_net_kernel<<<B / WPB, BLK, 0, stream>>>(x, W, bias, h, pvec, out);
}

// Round 5
// 55.244 us; speedup vs baseline: 6.6183x; 1.0215x over previous
//
#include <hip/hip_runtime.h>
#include <math.h>

#define NFEAT 32
#define EMB   30
#define ATT   10
#define NPAIR 496   // 32*31/2
#define BLK   128
#define WPB   2     // waves per block = batch elements per block
#define ROWSTR 36   // padded x-row stride in floats (144B; 4-bank shift per row)

typedef float v2f __attribute__((ext_vector_type(2)));

#define BC0(v) __builtin_shufflevector(v, v, 0, 0)
#define BC1(v) __builtin_shufflevector(v, v, 1, 1)

// R2 lesson: waves_per_eu(4) == 64-VGPR cap on this toolchain.
// R4: k=2 body fits (52 VGPR, no spill), VALUBusy 77%, occupancy ~34%,
//     56us -> now issue/latency mixed. This round: 2-wave blocks (finer
//     packing, 16 blocks/CU), packed products + packed pvec-accum,
//     max-first softmax tail.
__global__ __launch_bounds__(BLK) __attribute__((amdgpu_waves_per_eu(4)))
void attn_net_kernel(const float* __restrict__ x,
                     const float* __restrict__ W,
                     const float* __restrict__ bias,
                     const float* __restrict__ h,
                     const float* __restrict__ pvec,
                     float* __restrict__ out)
{
    __shared__ __align__(16) float sx[WPB * NFEAT * ROWSTR];  // 9 KiB

    const int t    = threadIdx.x;
    const int wid  = t >> 6;
    const int lane = t & 63;
    const int b    = blockIdx.x * WPB + wid;

    // ---- stage x[b] into this wave's padded LDS rows (wave-private: no barrier).
    //      cols 30..35 uninitialized: eg=7 consumes only e=28,29. ----
    float* swx = sx + wid * (NFEAT * ROWSTR);
    {
        const float4* xin = reinterpret_cast<const float4*>(x + (size_t)b * (NFEAT * EMB));
        for (int v = lane; v < 240; v += 64) {          // exactly 240 float4s
            const float4 d = xin[v];
            const int ef = 4 * v;
            #pragma unroll
            for (int u = 0; u < 4; ++u) {
                const int e = ef + u;
                const int r = e / EMB;
                const int c = e - r * EMB;
                swx[r * ROWSTR + c] = ((const float*)&d)[u];
            }
        }
    }

    // ---- uniform params (scalar s_loads -> SGPRs) ----
    v2f b2[5], h2[5];
    #pragma unroll
    for (int a2 = 0; a2 < 5; ++a2) {
        b2[a2] = v2f{bias[2 * a2], bias[2 * a2 + 1]};
        h2[a2] = v2f{h[2 * a2],    h[2 * a2 + 1]};
    }

    // ---- per-lane: 8 pairs in 4 chunks of 2; online softmax in (m,se,sec) ----
    float m = -INFINITY, se = 0.f, sec = 0.f;

    #pragma unroll
    for (int ch = 0; ch < 4; ++ch) {
        // closed-form triu index p -> (i,j); 3969-8p=(63-2i)^2 exact at row starts
        int oi[2], oj[2];
        #pragma unroll
        for (int k = 0; k < 2; ++k) {
            int p = lane + 64 * (ch * 2 + k);
            if (p > NPAIR - 1) p = NPAIR - 1;          // tail lanes masked below
            int i = (int)((63.0f - sqrtf((float)(3969 - 8 * p))) * 0.5f);
            if (i * (63 - i) / 2 > p) --i;
            if ((i + 1) * (62 - i) / 2 <= p) ++i;
            const int j = i + 1 + (p - i * (63 - i) / 2);
            oi[k] = i * ROWSTR;
            oj[k] = j * ROWSTR;
        }

        v2f acc2[2][5];                                 // a-packed accumulators (20 VGPR)
        v2f accC[2];                                    // e-pair-packed pvec accum
        #pragma unroll
        for (int k = 0; k < 2; ++k) {
            #pragma unroll
            for (int a2 = 0; a2 < 5; ++a2) acc2[k][a2] = b2[a2];
            accC[k] = v2f{0.f, 0.f};
        }

        #pragma unroll
        for (int eg = 0; eg < 8; ++eg) {                // e-groups of 4; eg=7 -> e=28,29 only
            v2f prL[2], prH[2];
            #pragma unroll
            for (int k = 0; k < 2; ++k) {
                const float4 xi = *reinterpret_cast<const float4*>(&swx[oi[k] + eg * 4]);
                const float4 xj = *reinterpret_cast<const float4*>(&swx[oj[k] + eg * 4]);
                const v2f* xiv = reinterpret_cast<const v2f*>(&xi);
                const v2f* xjv = reinterpret_cast<const v2f*>(&xj);
                prL[k] = xiv[0] * xjv[0];               // v_pk_mul_f32
                prH[k] = xiv[1] * xjv[1];
            }
            const int TMAX = (eg == 7) ? 2 : 4;
            #pragma unroll
            for (int t4 = 0; t4 < TMAX; ++t4) {
                const int e = eg * 4 + t4;
                const v2f w01 = v2f{W[e * ATT + 0], W[e * ATT + 1]};
                const v2f w23 = v2f{W[e * ATT + 2], W[e * ATT + 3]};
                const v2f w45 = v2f{W[e * ATT + 4], W[e * ATT + 5]};
                const v2f w67 = v2f{W[e * ATT + 6], W[e * ATT + 7]};
                const v2f w89 = v2f{W[e * ATT + 8], W[e * ATT + 9]};
                #pragma unroll
                for (int k = 0; k < 2; ++k) {
                    const v2f src = (t4 < 2) ? prL[k] : prH[k];
                    const v2f pe2 = (t4 & 1) ? BC1(src) : BC0(src);
                    acc2[k][0] = __builtin_elementwise_fma(pe2, w01, acc2[k][0]);
                    acc2[k][1] = __builtin_elementwise_fma(pe2, w23, acc2[k][1]);
                    acc2[k][2] = __builtin_elementwise_fma(pe2, w45, acc2[k][2]);
                    acc2[k][3] = __builtin_elementwise_fma(pe2, w67, acc2[k][3]);
                    acc2[k][4] = __builtin_elementwise_fma(pe2, w89, acc2[k][4]);
                }
            }
            // pvec accumulation, packed over e-pairs
            const int e0 = eg * 4;
            const v2f pv01 = v2f{pvec[e0], pvec[e0 + 1]};
            if (eg < 7) {
                const v2f pv23 = v2f{pvec[e0 + 2], pvec[e0 + 3]};
                #pragma unroll
                for (int k = 0; k < 2; ++k) {
                    accC[k] = __builtin_elementwise_fma(prL[k], pv01, accC[k]);
                    accC[k] = __builtin_elementwise_fma(prH[k], pv23, accC[k]);
                }
            } else {
                #pragma unroll
                for (int k = 0; k < 2; ++k)
                    accC[k] = __builtin_elementwise_fma(prL[k], pv01, accC[k]);
            }
        }

        float s2[2], cv2[2];
        #pragma unroll
        for (int k = 0; k < 2; ++k) {
            const v2f z = v2f{0.f, 0.f};
            v2f sv = z;
            #pragma unroll
            for (int a2 = 0; a2 < 5; ++a2) {
                const v2f r = __builtin_elementwise_max(acc2[k][a2], z);
                sv = __builtin_elementwise_fma(r, h2[a2], sv);
            }
            s2[k]  = sv.x + sv.y;
            cv2[k] = accC[k].x + accC[k].y;
            if (lane + 64 * (ch * 2 + k) >= NPAIR) s2[k] = -INFINITY;
        }

        // online merge (ch=0: m=-inf -> scale=0, clean start)
        const float nm = fmaxf(m, fmaxf(s2[0], s2[1]));
        const float scale = __expf(m - nm);
        se  *= scale;
        sec *= scale;
        #pragma unroll
        for (int k = 0; k < 2; ++k) {
            const float E = __expf(s2[k] - nm);         // exp(-inf)=0 for masked
            se += E;
            sec = fmaf(E, cv2[k], sec);
        }
        m = nm;
    }

    // ---- tail: global max first (short chain), one rescale, then add-butterflies ----
    float M = m;
    #pragma unroll
    for (int o = 1; o < 64; o <<= 1) M = fmaxf(M, __shfl_xor(M, o, 64));
    const float rs = __expf(m - M);
    se  *= rs;
    sec *= rs;
    #pragma unroll
    for (int o = 1; o < 64; o <<= 1) {
        se  += __shfl_xor(se,  o, 64);
        sec += __shfl_xor(sec, o, 64);
    }
    if (lane == 0) out[b] = sec / se;
}

extern "C" void kernel_launch(void* const* d_in, const int* in_sizes, int n_in,
                              void* d_out, int out_size, void* d_ws, size_t ws_size,
                              hipStream_t stream) {
    const float* x    = (const float*)d_in[0];
    const float* W    = (const float*)d_in[1];
    const float* bias = (const float*)d_in[2];
    const float* h    = (const float*)d_in[3];
    const float* pvec = (const float*)d_in[4];
    float* out = (float*)d_out;

    const int B = in_sizes[0] / (NFEAT * EMB);   // 8192
    attn_net_kernel<<<B / WPB, BLK, 0, stream>>>(x, W, bias, h, pvec, out);
}

// Round 6
// 53.483 us; speedup vs baseline: 6.8362x; 1.0329x over previous
//
#include <hip/hip_runtime.h>
#include <math.h>

#define NFEAT 32
#define EMB   30
#define ATT   10
#define NPAIR 496   // 32*31/2
#define BLK   128
#define WPB   2     // waves per block = batch elements per block
#define ROWSTR 36   // padded x-row stride in floats (144B; 4-bank shift per row)

typedef float v2f __attribute__((ext_vector_type(2)));

// Forced VOP3P: acc += broadcast(pr.lo or pr.hi) * w   (w in SGPR pair)
#define PK_FMA_BCLO(acc, pr, w) \
    asm("v_pk_fma_f32 %0, %1, %2, %0 op_sel:[0,0,0] op_sel_hi:[0,1,1]" \
        : "+v"(acc) : "v"(pr), "s"(w))
#define PK_FMA_BCHI(acc, pr, w) \
    asm("v_pk_fma_f32 %0, %1, %2, %0 op_sel:[1,0,0] op_sel_hi:[1,1,1]" \
        : "+v"(acc) : "v"(pr), "s"(w))
#define PK_FMA(acc, a, b) \
    asm("v_pk_fma_f32 %0, %1, %2, %0" : "+v"(acc) : "v"(a), "s"(b))
#define PK_MUL(d, a, b) \
    asm("v_pk_mul_f32 %0, %1, %2" : "=v"(d) : "v"(a), "v"(b))

// R5 lesson: v2f builtins did NOT cut VALU busy vs scalar (41-46us constant
// across rounds) -> compiler scalarizes or pads with movs. This round forces
// v_pk_fma_f32 + op_sel broadcasts via inline asm; sqrt fixups removed
// (exactness provable: margin >= 0.065 >> fp32 ulp at row boundaries).
__global__ __launch_bounds__(BLK) __attribute__((amdgpu_waves_per_eu(4)))
void attn_net_kernel(const float* __restrict__ x,
                     const float* __restrict__ W,
                     const float* __restrict__ bias,
                     const float* __restrict__ h,
                     const float* __restrict__ pvec,
                     float* __restrict__ out)
{
    __shared__ __align__(16) float sx[WPB * NFEAT * ROWSTR];  // 9 KiB

    const int t    = threadIdx.x;
    const int wid  = t >> 6;
    const int lane = t & 63;
    const int b    = blockIdx.x * WPB + wid;

    // ---- stage x[b] into this wave's padded LDS rows (wave-private: no barrier).
    //      cols 30..35 uninitialized: eg=7 consumes only e=28,29. ----
    float* swx = sx + wid * (NFEAT * ROWSTR);
    {
        const float4* xin = reinterpret_cast<const float4*>(x + (size_t)b * (NFEAT * EMB));
        for (int v = lane; v < 240; v += 64) {          // exactly 240 float4s
            const float4 d = xin[v];
            const int ef = 4 * v;
            #pragma unroll
            for (int u = 0; u < 4; ++u) {
                const int e = ef + u;
                const int r = e / EMB;
                const int c = e - r * EMB;
                swx[r * ROWSTR + c] = ((const float*)&d)[u];
            }
        }
    }

    // ---- uniform params (scalar s_loads -> SGPRs) ----
    v2f b2[5], h2[5];
    #pragma unroll
    for (int a2 = 0; a2 < 5; ++a2) {
        b2[a2] = v2f{bias[2 * a2], bias[2 * a2 + 1]};
        h2[a2] = v2f{h[2 * a2],    h[2 * a2 + 1]};
    }

    // ---- per-lane: 8 pairs in 4 chunks of 2; online softmax in (m,se,sec) ----
    float m = -INFINITY, se = 0.f, sec = 0.f;

    #pragma unroll
    for (int ch = 0; ch < 4; ++ch) {
        // closed-form triu index p -> (i,j); exact without fixups (see header)
        int oi[2], oj[2];
        #pragma unroll
        for (int k = 0; k < 2; ++k) {
            int p = lane + 64 * (ch * 2 + k);
            if (p > NPAIR - 1) p = NPAIR - 1;          // tail lanes masked below
            const float sq = sqrtf((float)(3969 - 8 * p));
            const int i = (int)((63.0f - sq) * 0.5f);
            const int j = i + 1 + (p - ((i * (63 - i)) >> 1));
            oi[k] = i * ROWSTR;
            oj[k] = j * ROWSTR;
        }

        v2f acc2[2][5];                                 // a-packed accumulators (20 VGPR)
        v2f accC[2];                                    // e-pair-packed pvec accum
        #pragma unroll
        for (int k = 0; k < 2; ++k) {
            #pragma unroll
            for (int a2 = 0; a2 < 5; ++a2) acc2[k][a2] = b2[a2];
            accC[k] = v2f{0.f, 0.f};
        }

        #pragma unroll
        for (int eg = 0; eg < 8; ++eg) {                // e-groups of 4; eg=7 -> e=28,29 only
            v2f prL[2], prH[2];
            #pragma unroll
            for (int k = 0; k < 2; ++k) {
                const float4 xi = *reinterpret_cast<const float4*>(&swx[oi[k] + eg * 4]);
                const float4 xj = *reinterpret_cast<const float4*>(&swx[oj[k] + eg * 4]);
                const v2f* xiv = reinterpret_cast<const v2f*>(&xi);
                const v2f* xjv = reinterpret_cast<const v2f*>(&xj);
                PK_MUL(prL[k], xiv[0], xjv[0]);
                PK_MUL(prH[k], xiv[1], xjv[1]);
            }
            const int e0 = eg * 4;
            // W rows for this e-group (uniform -> SGPR pairs)
            {   // e0 : broadcast prL.lo
                const v2f w0 = v2f{W[e0*ATT+0], W[e0*ATT+1]};
                const v2f w1 = v2f{W[e0*ATT+2], W[e0*ATT+3]};
                const v2f w2 = v2f{W[e0*ATT+4], W[e0*ATT+5]};
                const v2f w3 = v2f{W[e0*ATT+6], W[e0*ATT+7]};
                const v2f w4 = v2f{W[e0*ATT+8], W[e0*ATT+9]};
                #pragma unroll
                for (int k = 0; k < 2; ++k) {
                    PK_FMA_BCLO(acc2[k][0], prL[k], w0);
                    PK_FMA_BCLO(acc2[k][1], prL[k], w1);
                    PK_FMA_BCLO(acc2[k][2], prL[k], w2);
                    PK_FMA_BCLO(acc2[k][3], prL[k], w3);
                    PK_FMA_BCLO(acc2[k][4], prL[k], w4);
                }
            }
            {   // e0+1 : broadcast prL.hi
                const int e = e0 + 1;
                const v2f w0 = v2f{W[e*ATT+0], W[e*ATT+1]};
                const v2f w1 = v2f{W[e*ATT+2], W[e*ATT+3]};
                const v2f w2 = v2f{W[e*ATT+4], W[e*ATT+5]};
                const v2f w3 = v2f{W[e*ATT+6], W[e*ATT+7]};
                const v2f w4 = v2f{W[e*ATT+8], W[e*ATT+9]};
                #pragma unroll
                for (int k = 0; k < 2; ++k) {
                    PK_FMA_BCHI(acc2[k][0], prL[k], w0);
                    PK_FMA_BCHI(acc2[k][1], prL[k], w1);
                    PK_FMA_BCHI(acc2[k][2], prL[k], w2);
                    PK_FMA_BCHI(acc2[k][3], prL[k], w3);
                    PK_FMA_BCHI(acc2[k][4], prL[k], w4);
                }
            }
            if (eg < 7) {
                {   // e0+2 : broadcast prH.lo
                    const int e = e0 + 2;
                    const v2f w0 = v2f{W[e*ATT+0], W[e*ATT+1]};
                    const v2f w1 = v2f{W[e*ATT+2], W[e*ATT+3]};
                    const v2f w2 = v2f{W[e*ATT+4], W[e*ATT+5]};
                    const v2f w3 = v2f{W[e*ATT+6], W[e*ATT+7]};
                    const v2f w4 = v2f{W[e*ATT+8], W[e*ATT+9]};
                    #pragma unroll
                    for (int k = 0; k < 2; ++k) {
                        PK_FMA_BCLO(acc2[k][0], prH[k], w0);
                        PK_FMA_BCLO(acc2[k][1], prH[k], w1);
                        PK_FMA_BCLO(acc2[k][2], prH[k], w2);
                        PK_FMA_BCLO(acc2[k][3], prH[k], w3);
                        PK_FMA_BCLO(acc2[k][4], prH[k], w4);
                    }
                }
                {   // e0+3 : broadcast prH.hi
                    const int e = e0 + 3;
                    const v2f w0 = v2f{W[e*ATT+0], W[e*ATT+1]};
                    const v2f w1 = v2f{W[e*ATT+2], W[e*ATT+3]};
                    const v2f w2 = v2f{W[e*ATT+4], W[e*ATT+5]};
                    const v2f w3 = v2f{W[e*ATT+6], W[e*ATT+7]};
                    const v2f w4 = v2f{W[e*ATT+8], W[e*ATT+9]};
                    #pragma unroll
                    for (int k = 0; k < 2; ++k) {
                        PK_FMA_BCHI(acc2[k][0], prH[k], w0);
                        PK_FMA_BCHI(acc2[k][1], prH[k], w1);
                        PK_FMA_BCHI(acc2[k][2], prH[k], w2);
                        PK_FMA_BCHI(acc2[k][3], prH[k], w3);
                        PK_FMA_BCHI(acc2[k][4], prH[k], w4);
                    }
                }
            }
            // pvec accumulation, packed over e-pairs
            const v2f pv01 = v2f{pvec[e0], pvec[e0 + 1]};
            if (eg < 7) {
                const v2f pv23 = v2f{pvec[e0 + 2], pvec[e0 + 3]};
                #pragma unroll
                for (int k = 0; k < 2; ++k) {
                    PK_FMA(accC[k], prL[k], pv01);
                    PK_FMA(accC[k], prH[k], pv23);
                }
            } else {
                #pragma unroll
                for (int k = 0; k < 2; ++k)
                    PK_FMA(accC[k], prL[k], pv01);
            }
        }

        float s2[2], cv2[2];
        #pragma unroll
        for (int k = 0; k < 2; ++k) {
            const v2f z = v2f{0.f, 0.f};
            v2f sv = z;
            #pragma unroll
            for (int a2 = 0; a2 < 5; ++a2) {
                const v2f r = __builtin_elementwise_max(acc2[k][a2], z);
                sv = __builtin_elementwise_fma(r, h2[a2], sv);
            }
            s2[k]  = sv.x + sv.y;
            cv2[k] = accC[k].x + accC[k].y;
            if (lane + 64 * (ch * 2 + k) >= NPAIR) s2[k] = -INFINITY;
        }

        // online merge (ch=0: m=-inf -> scale=0, clean start)
        const float nm = fmaxf(m, fmaxf(s2[0], s2[1]));
        const float scale = __expf(m - nm);
        se  *= scale;
        sec *= scale;
        #pragma unroll
        for (int k = 0; k < 2; ++k) {
            const float E = __expf(s2[k] - nm);         // exp(-inf)=0 for masked
            se += E;
            sec = fmaf(E, cv2[k], sec);
        }
        m = nm;
    }

    // ---- tail: global max first (short chain), one rescale, then add-butterflies ----
    float M = m;
    #pragma unroll
    for (int o = 1; o < 64; o <<= 1) M = fmaxf(M, __shfl_xor(M, o, 64));
    const float rs = __expf(m - M);
    se  *= rs;
    sec *= rs;
    #pragma unroll
    for (int o = 1; o < 64; o <<= 1) {
        se  += __shfl_xor(se,  o, 64);
        sec += __shfl_xor(sec, o, 64);
    }
    if (lane == 0) out[b] = sec / se;
}

extern "C" void kernel_launch(void* const* d_in, const int* in_sizes, int n_in,
                              void* d_out, int out_size, void* d_ws, size_t ws_size,
                              hipStream_t stream) {
    const float* x    = (const float*)d_in[0];
    const float* W    = (const float*)d_in[1];
    const float* bias = (const float*)d_in[2];
    const float* h    = (const float*)d_in[3];
    const float* pvec = (const float*)d_in[4];
    float* out = (float*)d_out;

    const int B = in_sizes[0] / (NFEAT * EMB);   // 8192
    attn_net_kernel<<<B / WPB, BLK, 0, stream>>>(x, W, bias, h, pvec, out);
}

// Round 7
// 37.711 us; speedup vs baseline: 9.6955x; 1.4182x over previous
//
#include <hip/hip_runtime.h>
#include <math.h>

#define NFEAT 32
#define EMB   30
#define ATT   10
#define NPAIR 496   // 32*31/2
#define BLK   128
#define WPB   2     // waves per block = batch elements per block
#define ROWSTR 36   // padded x-row stride in floats (144B; 4-bank shift per row)

typedef float v2f __attribute__((ext_vector_type(2)));

// Forced VOP3P: acc += broadcast(pr.lo or pr.hi) * w   (w in SGPR pair)
#define PK_FMA_BCLO(acc, pr, w) \
    asm("v_pk_fma_f32 %0, %1, %2, %0 op_sel:[0,0,0] op_sel_hi:[0,1,1]" \
        : "+v"(acc) : "v"(pr), "s"(w))
#define PK_FMA_BCHI(acc, pr, w) \
    asm("v_pk_fma_f32 %0, %1, %2, %0 op_sel:[1,0,0] op_sel_hi:[1,1,1]" \
        : "+v"(acc) : "v"(pr), "s"(w))
#define PK_FMA(acc, a, b) \
    asm("v_pk_fma_f32 %0, %1, %2, %0" : "+v"(acc) : "v"(a), "s"(b))
#define PK_MUL(d, a, b) \
    asm("v_pk_mul_f32 %0, %1, %2" : "=v"(d) : "v"(a), "v"(b))

// R6 lesson: VALU was never the binding pipe (per-SIMD duty ~23%); the
// invariant cost is 128 ds_read_b128/wave (~20us/CU LDS pipe). This round:
// 2x2 (i,j) pair-tiles -> 4 pairs share 4 row-reads -> 64 ds_read_b128/wave.
// Exact cover: 120 off-diag 2x2 tiles (all slots valid) + 8 special tiles
// {4s,4s+2}x{4s+1,4s+3} for the 16 diagonal pairs (slots 1,2 masked) = 128
// tiles = 64 lanes x 2 chunks, no tail. wpe(3) (cap ~80+) for the ~73-reg
// body -- wpe(4)'s 64 cap would spill (R1/R2 lesson).
__global__ __launch_bounds__(BLK) __attribute__((amdgpu_waves_per_eu(3)))
void attn_net_kernel(const float* __restrict__ x,
                     const float* __restrict__ W,
                     const float* __restrict__ bias,
                     const float* __restrict__ h,
                     const float* __restrict__ pvec,
                     float* __restrict__ out)
{
    __shared__ __align__(16) float sx[WPB * NFEAT * ROWSTR];  // 9 KiB

    const int t    = threadIdx.x;
    const int wid  = t >> 6;
    const int lane = t & 63;
    const int b    = blockIdx.x * WPB + wid;

    // ---- stage x[b] into this wave's padded LDS rows (wave-private: no barrier).
    //      cols 30..35 uninitialized: eg=7 consumes only e=28,29. ----
    float* swx = sx + wid * (NFEAT * ROWSTR);
    {
        const float4* xin = reinterpret_cast<const float4*>(x + (size_t)b * (NFEAT * EMB));
        for (int v = lane; v < 240; v += 64) {          // exactly 240 float4s
            const float4 d = xin[v];
            const int ef = 4 * v;
            #pragma unroll
            for (int u = 0; u < 4; ++u) {
                const int e = ef + u;
                const int r = e / EMB;
                const int c = e - r * EMB;
                swx[r * ROWSTR + c] = ((const float*)&d)[u];
            }
        }
    }

    // ---- uniform params (scalar s_loads -> SGPRs) ----
    v2f b2[5], h2[5];
    #pragma unroll
    for (int a2 = 0; a2 < 5; ++a2) {
        b2[a2] = v2f{bias[2 * a2], bias[2 * a2 + 1]};
        h2[a2] = v2f{h[2 * a2],    h[2 * a2 + 1]};
    }

    // ---- per-lane: 2 chunks x one 2x2 tile (4 pairs); online softmax ----
    float m = -INFINITY, se = 0.f, sec = 0.f;

    #pragma unroll
    for (int ch = 0; ch < 2; ++ch) {
        const int T = ch * 64 + lane;
        const bool special = (T >= 120);                // only ch==1, lanes 56..63
        int r0, r1, c0, c1;
        if (special) {
            const int s7 = T - 120;
            r0 = 4 * s7; r1 = r0 + 2; c0 = r0 + 1; c1 = r0 + 3;
        } else {
            // n=16 triu inversion; exact: 961-8*T_I=(31-2I)^2, margin>=4/29
            const float sq = sqrtf((float)(961 - 8 * T));
            const int I = (int)((31.0f - sq) * 0.5f);
            const int J = I + 1 + (T - ((I * (31 - I)) >> 1));
            r0 = 2 * I; r1 = r0 + 1; c0 = 2 * J; c1 = c0 + 1;
        }
        const int oi0 = r0 * ROWSTR, oi1 = r1 * ROWSTR;
        const int oj0 = c0 * ROWSTR, oj1 = c1 * ROWSTR;

        // slots: 0:(r0,c0) 1:(r0,c1) 2:(r1,c0) 3:(r1,c1); special masks 1,2
        v2f acc[4][5];                                  // 40 VGPR
        v2f accC[4];                                    // 8 VGPR (e-pair packed)
        #pragma unroll
        for (int p = 0; p < 4; ++p) {
            #pragma unroll
            for (int a2 = 0; a2 < 5; ++a2) acc[p][a2] = b2[a2];
            accC[p] = v2f{0.f, 0.f};
        }

        #pragma unroll
        for (int eg = 0; eg < 8; ++eg) {                // e-groups of 4; eg=7 -> e=28,29
            const int e0 = eg * 4;
            const bool full = (eg < 7);
            // W rows for this e-group -> SGPR pairs (shared by all 4 pairs)
            v2f wa[5], wb[5], wc[5], wd[5];
            #pragma unroll
            for (int a2 = 0; a2 < 5; ++a2) {
                wa[a2] = v2f{W[(e0    ) * ATT + 2*a2], W[(e0    ) * ATT + 2*a2 + 1]};
                wb[a2] = v2f{W[(e0 + 1) * ATT + 2*a2], W[(e0 + 1) * ATT + 2*a2 + 1]};
            }
            if (full) {
                #pragma unroll
                for (int a2 = 0; a2 < 5; ++a2) {
                    wc[a2] = v2f{W[(e0 + 2) * ATT + 2*a2], W[(e0 + 2) * ATT + 2*a2 + 1]};
                    wd[a2] = v2f{W[(e0 + 3) * ATT + 2*a2], W[(e0 + 3) * ATT + 2*a2 + 1]};
                }
            }
            const v2f pv01 = v2f{pvec[e0], pvec[e0 + 1]};
            v2f pv23 = v2f{0.f, 0.f};
            if (full) pv23 = v2f{pvec[e0 + 2], pvec[e0 + 3]};

            const float4 xi0 = *reinterpret_cast<const float4*>(&swx[oi0 + e0]);
            const float4 xi1 = *reinterpret_cast<const float4*>(&swx[oi1 + e0]);

            auto do_pair = [&](v2f* ap, v2f& cp, const float4& xi, const float4& xj) {
                const v2f* xiv = reinterpret_cast<const v2f*>(&xi);
                const v2f* xjv = reinterpret_cast<const v2f*>(&xj);
                v2f prL;
                PK_MUL(prL, xiv[0], xjv[0]);
                #pragma unroll
                for (int a2 = 0; a2 < 5; ++a2) PK_FMA_BCLO(ap[a2], prL, wa[a2]);
                #pragma unroll
                for (int a2 = 0; a2 < 5; ++a2) PK_FMA_BCHI(ap[a2], prL, wb[a2]);
                PK_FMA(cp, prL, pv01);
                if (full) {
                    v2f prH;
                    PK_MUL(prH, xiv[1], xjv[1]);
                    #pragma unroll
                    for (int a2 = 0; a2 < 5; ++a2) PK_FMA_BCLO(ap[a2], prH, wc[a2]);
                    #pragma unroll
                    for (int a2 = 0; a2 < 5; ++a2) PK_FMA_BCHI(ap[a2], prH, wd[a2]);
                    PK_FMA(cp, prH, pv23);
                }
            };

            {   // column j0: pairs (r0,c0)->slot0, (r1,c0)->slot2
                const float4 xj = *reinterpret_cast<const float4*>(&swx[oj0 + e0]);
                do_pair(acc[0], accC[0], xi0, xj);
                do_pair(acc[2], accC[2], xi1, xj);
            }
            {   // column j1: pairs (r0,c1)->slot1, (r1,c1)->slot3
                const float4 xj = *reinterpret_cast<const float4*>(&swx[oj1 + e0]);
                do_pair(acc[1], accC[1], xi0, xj);
                do_pair(acc[3], accC[3], xi1, xj);
            }
        }

        float s4[4], cv4[4];
        #pragma unroll
        for (int p = 0; p < 4; ++p) {
            const v2f z = v2f{0.f, 0.f};
            v2f sv = z;
            #pragma unroll
            for (int a2 = 0; a2 < 5; ++a2) {
                const v2f r = __builtin_elementwise_max(acc[p][a2], z);
                sv = __builtin_elementwise_fma(r, h2[a2], sv);
            }
            s4[p]  = sv.x + sv.y;
            cv4[p] = accC[p].x + accC[p].y;
        }
        if (special) { s4[1] = -INFINITY; s4[2] = -INFINITY; }  // dup / i>j slots

        // online merge (ch=0: m=-inf -> scale=0, clean start)
        const float nm = fmaxf(m, fmaxf(fmaxf(s4[0], s4[1]), fmaxf(s4[2], s4[3])));
        const float scale = __expf(m - nm);
        se  *= scale;
        sec *= scale;
        #pragma unroll
        for (int p = 0; p < 4; ++p) {
            const float E = __expf(s4[p] - nm);         // exp(-inf)=0 for masked
            se += E;
            sec = fmaf(E, cv4[p], sec);
        }
        m = nm;
    }

    // ---- tail: global max first, one rescale, then add-butterflies ----
    float M = m;
    #pragma unroll
    for (int o = 1; o < 64; o <<= 1) M = fmaxf(M, __shfl_xor(M, o, 64));
    const float rs = __expf(m - M);
    se  *= rs;
    sec *= rs;
    #pragma unroll
    for (int o = 1; o < 64; o <<= 1) {
        se  += __shfl_xor(se,  o, 64);
        sec += __shfl_xor(sec, o, 64);
    }
    if (lane == 0) out[b] = sec / se;
}

extern "C" void kernel_launch(void* const* d_in, const int* in_sizes, int n_in,
                              void* d_out, int out_size, void* d_ws, size_t ws_size,
                              hipStream_t stream) {
    const float* x    = (const float*)d_in[0];
    const float* W    = (const float*)d_in[1];
    const float* bias = (const float*)d_in[2];
    const float* h    = (const float*)d_in[3];
    const float* pvec = (const float*)d_in[4];
    float* out = (float*)d_out;

    const int B = in_sizes[0] / (NFEAT * EMB);   // 8192
    attn_net_kernel<<<B / WPB, BLK, 0, stream>>>(x, W, bias, h, pvec, out);
}